// Round 11
// baseline (275.025 us; speedup 1.0000x reference)
//
#include <hip/hip_runtime.h>

// Problem constants
#define BQ   512   // batch
#define SEQ  128   // L
#define IND  256   // INPUT_DIM
#define POSD 32
#define EMB  512
#define NH   4
#define HDIM 128
#define OUTD 256

// ---------------------------------------------------------------------------
// tile64: 64x64 output tile GEMM (exact arithmetic of r4/r7 PASSING kernels).
// ---------------------------------------------------------------------------
template<bool BT>
__device__ __forceinline__ void tile64(const float* __restrict__ A, int lda,
                                       const float* __restrict__ B, int ldb,
                                       int K,
                                       float* __restrict__ C, int ldc,
                                       const float* __restrict__ bias,
                                       float (*As)[68], float (*Bs)[68])
{
    const int tid = threadIdx.x;
    const int tx  = tid & 15;
    const int ty  = tid >> 4;
    const int bn  = tid & 63;
    const int bk  = tid >> 6;

    float acc[4][4] = {{0.f}};

    for (int k0 = 0; k0 < K; k0 += 16) {
        #pragma unroll
        for (int i = 0; i < 4; i++)
            As[tx][ty + i * 16] = A[(long)(ty + i * 16) * lda + (k0 + tx)];
        if (BT) {
            #pragma unroll
            for (int i = 0; i < 4; i++)
                Bs[tx][ty + i * 16] = B[(long)(ty + i * 16) * ldb + (k0 + tx)];
        } else {
            #pragma unroll
            for (int i = 0; i < 4; i++)
                Bs[bk + i * 4][bn] = B[(long)(k0 + bk + i * 4) * ldb + bn];
        }
        __syncthreads();
        #pragma unroll
        for (int kk = 0; kk < 16; kk++) {
            float a4[4], b4[4];
            *(float4*)a4 = *(const float4*)&As[kk][ty * 4];
            *(float4*)b4 = *(const float4*)&Bs[kk][tx * 4];
            #pragma unroll
            for (int i = 0; i < 4; i++)
                #pragma unroll
                for (int j = 0; j < 4; j++)
                    acc[i][j] = fmaf(a4[i], b4[j], acc[i][j]);
        }
        __syncthreads();
    }

    const int gn = tx * 4;
    #pragma unroll
    for (int i = 0; i < 4; i++) {
        const int gm = ty * 4 + i;
        float4 v;
        v.x = acc[i][0]; v.y = acc[i][1]; v.z = acc[i][2]; v.w = acc[i][3];
        if (bias) {
            const float4 bv = *(const float4*)(bias + gn);
            v.x += bv.x; v.y += bv.y; v.z += bv.z; v.w += bv.w;
        }
        *(float4*)&C[(long)gm * ldc + gn] = v;
    }
}

// ---------------------------------------------------------------------------
// tile128: 128x128 output tile, 256 thr, 8x8 per thread (rows {ty*4+i,
// 64+ty*4+i}, cols {tx*4+j, 64+tx*4+j}) — 67% VALU/LDS efficiency vs
// tile64's 33%; all LDS reads <=2-way bank aliasing.
// ---------------------------------------------------------------------------
__device__ __forceinline__ void tile128(const float* __restrict__ A, int lda,
                                        const float* __restrict__ B, int ldb,
                                        int K,
                                        float* __restrict__ C, int ldc,
                                        float (*As)[132], float (*Bs)[132])
{
    const int tid = threadIdx.x;
    const int tx  = tid & 15;
    const int ty  = tid >> 4;
    const int bn  = tid & 127;
    const int bk  = tid >> 7;

    float acc[8][8];
    #pragma unroll
    for (int i = 0; i < 8; i++)
        #pragma unroll
        for (int j = 0; j < 8; j++) acc[i][j] = 0.f;

    for (int k0 = 0; k0 < K; k0 += 16) {
        #pragma unroll
        for (int i = 0; i < 8; i++)
            As[tx][ty + i * 16] = A[(long)(ty + i * 16) * lda + (k0 + tx)];
        #pragma unroll
        for (int i = 0; i < 8; i++)
            Bs[bk + i * 2][bn] = B[(long)(k0 + bk + i * 2) * ldb + bn];
        __syncthreads();
        #pragma unroll
        for (int kk = 0; kk < 16; kk++) {
            float a8[8], b8[8];
            *(float4*)&a8[0] = *(const float4*)&As[kk][ty * 4];
            *(float4*)&a8[4] = *(const float4*)&As[kk][64 + ty * 4];
            *(float4*)&b8[0] = *(const float4*)&Bs[kk][tx * 4];
            *(float4*)&b8[4] = *(const float4*)&Bs[kk][64 + tx * 4];
            #pragma unroll
            for (int i = 0; i < 8; i++)
                #pragma unroll
                for (int j = 0; j < 8; j++)
                    acc[i][j] = fmaf(a8[i], b8[j], acc[i][j]);
        }
        __syncthreads();
    }

    #pragma unroll
    for (int ih = 0; ih < 2; ih++) {
        #pragma unroll
        for (int i = 0; i < 4; i++) {
            const int gm = ih * 64 + ty * 4 + i;
            #pragma unroll
            for (int jh = 0; jh < 2; jh++) {
                const int gn = jh * 64 + tx * 4;
                float4 v;
                v.x = acc[ih * 4 + i][jh * 4 + 0];
                v.y = acc[ih * 4 + i][jh * 4 + 1];
                v.z = acc[ih * 4 + i][jh * 4 + 2];
                v.w = acc[ih * 4 + i][jh * 4 + 3];
                *(float4*)&C[(long)gm * ldc + gn] = v;
            }
        }
    }
}

// ---------------------------------------------------------------------------
// Node-overhead probe: trivial kernel; 8 of these prepended. Writes into
// PART which is fully overwritten afterwards (no correctness impact).
// ---------------------------------------------------------------------------
__global__ void dummy_k(float* __restrict__ p, int i)
{
    if (threadIdx.x == 0) p[i] = 1.0f;
}

// ---------------------------------------------------------------------------
// pos_pb (r4/r7, passed)
// ---------------------------------------------------------------------------
__global__ __launch_bounds__(256)
void pos_pb_k(const float* __restrict__ W_r, const float* __restrict__ W_embed,
              const float* __restrict__ b_embed, float* __restrict__ PB)
{
    __shared__ float rr[POSD];
    const int p   = blockIdx.x;        // 0..127
    const int tid = threadIdx.x;

    if (tid < POSD) {
        const int pos = (SEQ - 1) - p;  // flip axis 0
        float acc = 0.f;
        #pragma unroll
        for (int i = 0; i < POSD; i++) {
            float expo  = powf(10000.0f, (2.0f * i) / (float)POSD);
            float angle = (float)pos / expo;
            float Ri    = ((i & 1) == 0) ? sinf(angle) : cosf(angle);
            acc = fmaf(Ri, W_r[i * POSD + tid], acc);
        }
        rr[tid] = acc;
    }
    __syncthreads();

    for (int c = tid; c < EMB; c += 256) {
        float acc = b_embed[c];
        #pragma unroll
        for (int i = 0; i < POSD; i++)
            acc = fmaf(rr[i], W_embed[(IND + i) * EMB + c], acc);
        PB[p * EMB + c] = acc;
    }
}

// ---------------------------------------------------------------------------
// wfpq with tile128, split-K x8 (K=64): grid (12, 3, 8).
// Partials [8][384][1536]; rows 0..255 = W_embed part, 256..383 = PB part
// (128-row tiles at 0/128/256 never straddle the boundary).
// ---------------------------------------------------------------------------
__global__ __launch_bounds__(256)
void wfpq128_k(const float* __restrict__ W_embed, const float* __restrict__ PB,
               const float* __restrict__ W_attn, float* __restrict__ P)
{
    __shared__ float As[16][132];
    __shared__ float Bs[16][132];
    const int ks = blockIdx.z;           // 0..7, K chunk base = ks*64
    const int kb = ks * 64;
    const int m0 = blockIdx.y * 128;     // 0, 128, 256
    const int n0 = blockIdx.x * 128;
    const float* Arow = (m0 < 256) ? (W_embed + (long)m0 * 512)
                                   : (PB + (long)(m0 - 256) * 512);
    tile128(Arow + kb, 512,
            W_attn + (long)kb * 1536 + n0, 1536, 64,
            P + (long)ks * 589824 + (long)m0 * 1536 + n0, 1536,
            As, Bs);
}

// ---------------------------------------------------------------------------
// Generic partial reduce (r4/r7, passed)
// ---------------------------------------------------------------------------
template<bool RELU>
__global__ __launch_bounds__(256)
void reduce_k(const float* __restrict__ P, long pStep, int nsl,
              const float* __restrict__ bias, int biasStartRow, int ldn,
              float* __restrict__ C)
{
    const long e = ((long)blockIdx.x * 256 + threadIdx.x) * 4;
    float4 s = *(const float4*)(P + e);
    for (int i = 1; i < nsl; i++) {
        const float4 p = *(const float4*)(P + (long)i * pStep + e);
        s.x += p.x; s.y += p.y; s.z += p.z; s.w += p.w;
    }
    if (bias) {
        const int row = (int)(e / ldn);
        if (row >= biasStartRow) {
            const int col = (int)(e % ldn);
            const float4 bv = *(const float4*)(bias + col);
            s.x += bv.x; s.y += bv.y; s.z += bv.z; s.w += bv.w;
        }
    }
    if (RELU) {
        s.x = fmaxf(s.x, 0.f); s.y = fmaxf(s.y, 0.f);
        s.z = fmaxf(s.z, 0.f); s.w = fmaxf(s.w, 0.f);
    }
    *(float4*)(C + e) = s;
}

// ---------------------------------------------------------------------------
// Q + G1 + G2 fused dispatch (r7, HW-verified): 256 blocks.
// ---------------------------------------------------------------------------
__global__ __launch_bounds__(256)
void qg_k(const float* __restrict__ hist, const float* __restrict__ WfPQ,
          const float* __restrict__ W_proj,
          float* __restrict__ Q, float* __restrict__ G1, float* __restrict__ G2)
{
    __shared__ float As[16][68];
    __shared__ float Bs[16][68];
    const int t = blockIdx.x;
    if (t < 64) {
        const int m0 = (t >> 3) * 64, n0 = (t & 7) * 64;
        tile64<false>(hist + 127 * IND + (long)m0 * (SEQ * IND), SEQ * IND,
                      WfPQ + n0, 1536, 256,
                      Q + (long)m0 * 512 + n0, 512,
                      WfPQ + (long)(256 + 127) * 1536 + n0, As, Bs);
    } else if (t < 128) {
        const int i = t - 64, h = i >> 4, r2 = i & 15;
        const int m0 = (r2 >> 3) * 64, n0 = (r2 & 7) * 64;
        tile64<false>(WfPQ + 256 * 1536 + 1024 + h * 128 + (long)m0 * 1536, 1536,
                      W_proj + (long)h * 128 * 512 + n0, 512, 128,
                      G1 + (long)h * 65536 + (long)m0 * 512 + n0, 512,
                      nullptr, As, Bs);
    } else {
        const int i = t - 128, h = i >> 5, r2 = i & 31;
        const int m0 = (r2 >> 3) * 64, n0 = (r2 & 7) * 64;
        tile64<false>(WfPQ + 1024 + h * 128 + (long)m0 * 1536, 1536,
                      W_proj + (long)h * 128 * 512 + n0, 512, 128,
                      G2 + (long)h * 131072 + (long)m0 * 512 + n0, 512,
                      nullptr, As, Bs);
    }
}

// ---------------------------------------------------------------------------
// T + SP fused (r7, HW-verified): 192 blocks, B transposed.
// ---------------------------------------------------------------------------
__global__ __launch_bounds__(256)
void tsp_k(const float* __restrict__ Q, const float* __restrict__ WfPQ,
           float* __restrict__ T, float* __restrict__ SP)
{
    __shared__ float As[16][68];
    __shared__ float Bs[16][68];
    const int t = blockIdx.x;
    if (t < 128) {
        const int h = t >> 5, i = t & 31;
        const int m0 = (i >> 2) * 64, n0 = (i & 3) * 64;
        tile64<true>(Q + h * 128 + (long)m0 * 512, 512,
                     WfPQ + 512 + h * 128 + (long)n0 * 1536, 1536, 128,
                     T + (long)h * 131072 + (long)m0 * 256 + n0, 256,
                     nullptr, As, Bs);
    } else {
        const int i = t - 128, h = i >> 4, j = i & 15;
        const int m0 = (j >> 1) * 64, n0 = (j & 1) * 64;
        tile64<true>(Q + h * 128 + (long)m0 * 512, 512,
                     WfPQ + 256 * 1536 + 512 + h * 128 + (long)n0 * 1536, 1536, 128,
                     SP + (long)h * 65536 + (long)m0 * 128 + n0, 128,
                     nullptr, As, Bs);
    }
}

// ---------------------------------------------------------------------------
// Per-batch attention for the last query row (UNCHANGED; passed r4/r6/r7).
// ---------------------------------------------------------------------------
__global__ __launch_bounds__(512)
void attn_k(const float* __restrict__ hist,
            const float* __restrict__ T,    // [4][512][256]
            const float* __restrict__ SP,   // [4][512][128]
            float* __restrict__ ATN,        // [4][512][128]
            float* __restrict__ U)          // [4][512][256]
{
    const int b   = blockIdx.x;
    const int tid = threadIdx.x;

    __shared__ float x[SEQ][IND + 1];
    __shared__ float t[NH][IND];
    __shared__ float sc[NH][SEQ];
    __shared__ float tmp[NH][SEQ];

    const float4* src = (const float4*)(hist + (long)b * SEQ * IND);
    #pragma unroll
    for (int i = 0; i < 16; i++) {
        int idx = tid + i * 512;
        int k   = idx >> 6;
        int j4  = (idx & 63) << 2;
        float4 v = src[idx];
        x[k][j4 + 0] = v.x; x[k][j4 + 1] = v.y;
        x[k][j4 + 2] = v.z; x[k][j4 + 3] = v.w;
    }
    #pragma unroll
    for (int i = 0; i < 2; i++) {
        int idx = tid + i * 512;
        int h = idx >> 8, j = idx & 255;
        t[h][j] = T[(long)h * (BQ * IND) + (long)b * IND + j];
    }
    {
        int h = tid >> 7, k = tid & 127;
        sc[h][k] = SP[(long)h * (BQ * SEQ) + b * SEQ + k];
    }
    __syncthreads();

    const int h = tid >> 7;
    const int k = tid & 127;
    const float* xr = &x[k][0];
    const float* tr = &t[h][0];
    float sraw = 0.f;
    #pragma unroll 8
    for (int j = 0; j < IND; j++)
        sraw = fmaf(xr[j], tr[j], sraw);
    const float s = (sraw + sc[h][k]) * 0.08838834764831845f;

    tmp[h][k] = s;
    __syncthreads();
    for (int st = 64; st > 0; st >>= 1) {
        if (k < st) tmp[h][k] = fmaxf(tmp[h][k], tmp[h][k + st]);
        __syncthreads();
    }
    const float mx_ = tmp[h][0];
    __syncthreads();
    const float e = expf(s - mx_);
    tmp[h][k] = e;
    __syncthreads();
    for (int st = 64; st > 0; st >>= 1) {
        if (k < st) tmp[h][k] += tmp[h][k + st];
        __syncthreads();
    }
    const float a = e / tmp[h][0];
    sc[h][k] = a;
    ATN[(long)h * (BQ * SEQ) + b * SEQ + k] = a;
    __syncthreads();

    const int j  = tid & 255;
    const int hh = tid >> 8;
    const float* a0 = &sc[hh][0];
    const float* a1 = &sc[hh + 2][0];
    float u0 = 0.f, u1 = 0.f;
    #pragma unroll 4
    for (int kk = 0; kk < SEQ; kk++) {
        float xv = x[kk][j];
        u0 = fmaf(a0[kk], xv, u0);
        u1 = fmaf(a1[kk], xv, u1);
    }
    U[(long)hh       * (BQ * IND) + b * IND + j] = u0;
    U[(long)(hh + 2) * (BQ * IND) + b * IND + j] = u1;
}

// ---------------------------------------------------------------------------
// O1 split-K partials with tile128: [12][512][512], grid (4, 4, 12).
// Same A/B selection as r7's o1_sk_k (HW-verified), bigger tiles.
// ---------------------------------------------------------------------------
__global__ __launch_bounds__(256)
void o1_128_k(const float* __restrict__ ATN, const float* __restrict__ U,
              const float* __restrict__ G1, const float* __restrict__ G2,
              float* __restrict__ P)
{
    __shared__ float As[16][132];
    __shared__ float Bs[16][132];
    const int c  = blockIdx.z;
    const int m0 = blockIdx.y * 128, n0 = blockIdx.x * 128;
    const float* A; int lda; const float* B;
    if (c < 4) {
        A = ATN + (long)c * 65536 + (long)m0 * 128; lda = 128;
        B = G1 + (long)c * 65536 + n0;
    } else {
        const int h = (c - 4) >> 1, q = (c - 4) & 1;
        A = U + (long)h * 131072 + q * 128 + (long)m0 * 256; lda = 256;
        B = G2 + (long)h * 131072 + (long)q * 65536 + n0;
    }
    tile128(A, lda, B, 512, 128,
            P + (long)c * 262144 + (long)m0 * 512 + n0, 512,
            As, Bs);
}

// ---------------------------------------------------------------------------
// MLP split-K x8 (K=64 chunks) — r7, HW-verified. grid (8, 8, 8).
// ---------------------------------------------------------------------------
__global__ __launch_bounds__(256)
void mlp_sk_k(const float* __restrict__ A0, const float* __restrict__ W,
              float* __restrict__ P)
{
    __shared__ float As[16][68];
    __shared__ float Bs[16][68];
    const int c  = blockIdx.z;
    const int m0 = blockIdx.y * 64, n0 = blockIdx.x * 64;
    tile64<false>(A0 + c * 64 + (long)m0 * 512, 512,
                  W + (long)c * 64 * 512 + n0, 512, 64,
                  P + (long)c * 262144 + (long)m0 * 512 + n0, 512,
                  nullptr, As, Bs);
}

// ---------------------------------------------------------------------------
// XP partials [6][512][256] — r7, HW-verified. grid (4, 8, 6).
// ---------------------------------------------------------------------------
__global__ __launch_bounds__(256)
void xp_sk_k(const float* __restrict__ X2, const float* __restrict__ W5,
             const float* __restrict__ hist, const float* __restrict__ W_skip,
             float* __restrict__ P)
{
    __shared__ float As[16][68];
    __shared__ float Bs[16][68];
    const int c  = blockIdx.z;
    const int m0 = blockIdx.y * 64, n0 = blockIdx.x * 64;
    const float* A; int lda; const float* B;
    if (c < 4) {
        A = X2 + c * 128 + (long)m0 * 512; lda = 512;
        B = W5 + (long)c * 128 * 256 + n0;
    } else if (c == 4) {
        A = hist + (long)m0 * (SEQ * IND); lda = SEQ * IND;
        B = W_skip + n0;
    } else {
        A = hist + 128 + (long)m0 * (SEQ * IND); lda = SEQ * IND;
        B = W_skip + 128 * 256 + n0;
    }
    tile64<false>(A, lda, B, 256, 128,
                  P + (long)c * 131072 + (long)m0 * 256 + n0, 256,
                  nullptr, As, Bs);
}

// ---------------------------------------------------------------------------
// Final (r4/r7, passed)
// ---------------------------------------------------------------------------
__global__ __launch_bounds__(256)
void final_k(const float* __restrict__ P,
             const float* __restrict__ b5, const float* __restrict__ b_skip,
             float* __restrict__ out)
{
    const int b = blockIdx.x, tid = threadIdx.x;
    const long e = (long)b * OUTD + tid;
    float v = b5[tid] + b_skip[tid];
    #pragma unroll
    for (int s = 0; s < 6; s++)
        v += P[(long)s * (BQ * OUTD) + e];
    v = fmaxf(v, 0.f);

    __shared__ float mn[4], mx[4];
    float lo = v, hi = v;
    #pragma unroll
    for (int off = 32; off > 0; off >>= 1) {
        lo = fminf(lo, __shfl_down(lo, off));
        hi = fmaxf(hi, __shfl_down(hi, off));
    }
    const int w = tid >> 6;
    if ((tid & 63) == 0) { mn[w] = lo; mx[w] = hi; }
    __syncthreads();
    if (tid == 0) {
        float l0 = mn[0], h0 = mx[0];
        for (int i = 1; i < 4; i++) { l0 = fminf(l0, mn[i]); h0 = fmaxf(h0, mx[i]); }
        mn[0] = l0; mx[0] = h0;
    }
    __syncthreads();
    const float lo0 = mn[0], hi0 = mx[0];
    out[e] = 2.f * (v - lo0) / (hi0 - lo0) - 1.f;
}

// ---------------------------------------------------------------------------
extern "C" void kernel_launch(void* const* d_in, const int* in_sizes, int n_in,
                              void* d_out, int out_size, void* d_ws, size_t ws_size,
                              hipStream_t stream)
{
    const float* hist    = (const float*)d_in[0];
    // d_in[1] end_pos: provably unused — for the last query row (q=L-1),
    // k_idx - q_idx <= 0 < end_pos (end_pos >= 1), so the mask never fires.
    const float* W_embed = (const float*)d_in[2];
    const float* b_embed = (const float*)d_in[3];
    const float* W_r     = (const float*)d_in[4];
    const float* W_attn  = (const float*)d_in[5];
    const float* b_attn  = (const float*)d_in[6];
    const float* W_proj  = (const float*)d_in[7];
    const float* b_proj  = (const float*)d_in[8];
    const float* W_skip  = (const float*)d_in[9];
    const float* b_skip  = (const float*)d_in[10];
    const float* W1      = (const float*)d_in[11];
    const float* b1      = (const float*)d_in[12];
    const float* W2      = (const float*)d_in[13];
    const float* b2      = (const float*)d_in[14];
    const float* W5      = (const float*)d_in[15];
    const float* b5      = (const float*)d_in[16];
    float* out = (float*)d_out;
    float* ws  = (float*)d_ws;
    (void)in_sizes; (void)n_in; (void)out_size; (void)ws_size;

    // workspace layout (float offsets); PART grown to 8 wfpq slices
    float* PB   = ws;                 //  65536   [128][512]
    float* WfPQ = ws + 65536;         // 589824   rows 0-255 Wf | 256-383 PQ, ld 1536
    float* Q    = ws + 655360;        // 262144   [512][512]
    float* G1   = ws + 917504;        // 262144   [4][128][512]
    float* G2   = ws + 1179648;       // 524288   [4][256][512]
    float* T    = ws + 1703936;       // 524288   [4][512][256]
    float* SP   = ws + 2228224;       // 262144   [4][512][128]
    float* ATN  = ws + 2490368;       // 262144   [4][512][128]
    float* U    = ws + 2752512;       // 524288   [4][512][256]
    float* PART = ws + 3276800;       // 4718592  max(8x384x1536, 12x512x512)
    float* O1   = ws + 7995392;       // 262144
    float* X1   = ws + 8257536;       // 262144
    float* X2   = ws + 8519680;       // 262144

    // 0) node-overhead probe: 8 trivial launches (PART overwritten later)
    for (int i = 0; i < 8; i++)
        dummy_k<<<1, 64, 0, stream>>>(PART, i);

    // 1) positional basis + pos_bias
    pos_pb_k<<<SEQ, 256, 0, stream>>>(W_r, W_embed, b_embed, PB);
    // 2) WfPQ split-K x8 partials, tile128  (288 blocks)
    wfpq128_k<<<dim3(12, 3, 8), 256, 0, stream>>>(W_embed, PB, W_attn, PART);
    // 3) reduce 8 -> WfPQ (+ b_attn on rows >= 256)
    reduce_k<false><<<576, 256, 0, stream>>>(PART, 589824, 8, b_attn, 256, 1536, WfPQ);
    // 4) Q + G1 + G2 (256 blocks)
    qg_k<<<256, 256, 0, stream>>>(hist, WfPQ, W_proj, Q, G1, G2);
    // 5) T + SP (192 blocks)
    tsp_k<<<192, 256, 0, stream>>>(Q, WfPQ, T, SP);
    // 6) attention (512 blocks)
    attn_k<<<BQ, 512, 0, stream>>>(hist, T, SP, ATN, U);
    // 7) O1 split-K partials, tile128 (192 blocks)
    o1_128_k<<<dim3(4, 4, 12), 256, 0, stream>>>(ATN, U, G1, G2, PART);
    // 8) reduce 12 + b_proj -> O1
    reduce_k<false><<<256, 256, 0, stream>>>(PART, 262144, 12, b_proj, 0, 512, O1);
    // 9) X1 split-K x8 partials (512 blocks)
    mlp_sk_k<<<dim3(8, 8, 8), 256, 0, stream>>>(O1, W1, PART);
    // 10) reduce 8 + b1 + relu -> X1
    reduce_k<true><<<256, 256, 0, stream>>>(PART, 262144, 8, b1, 0, 512, X1);
    // 11) X2 split-K x8 partials (512 blocks)
    mlp_sk_k<<<dim3(8, 8, 8), 256, 0, stream>>>(X1, W2, PART);
    // 12) reduce 8 + b2 + relu -> X2
    reduce_k<true><<<256, 256, 0, stream>>>(PART, 262144, 8, b2, 0, 512, X2);
    // 13) XP partials: X2@W5 (4) + hist0@W_skip (2)  (192 blocks)
    xp_sk_k<<<dim3(4, 8, 6), 256, 0, stream>>>(X2, W5, hist, W_skip, PART);
    // 14) final: sum 6 partials + biases, relu, minmax normalize
    final_k<<<BQ, 256, 0, stream>>>(PART, b5, b_skip, out);
}